// Round 19
// baseline (2527.064 us; speedup 1.0000x reference)
//
#include <hip/hip_runtime.h>
#include <cstdint>

#define T_ 4
#define B_ 16
#define N_ 256
#define C_ 512
#define H_ 8
#define HID_ 2048
#define M_ (T_*B_*N_)      // 16384 rows
#define BNP_ (B_*N_)       // 4096 (b,n) pairs

// ---------------------------------------------------------------------------
// f32 GEMM, 128x128 tile, 8x8 micro, double-buffered, conflict-free fragment
// map. BIT-IDENTICAL per-element math to R1. Used for f1. (R16-verbatim)
// ---------------------------------------------------------------------------
__global__ __launch_bounds__(256, 2)
void gemm_f32_t128(const float* __restrict__ A, const float* __restrict__ W,
                   const float* __restrict__ bias, float* __restrict__ Y,
                   int Nc, int K) {
  __shared__ float As[2][16][132];
  __shared__ float Ws[2][16][132];
  const int tid  = threadIdx.x;
  const int row0 = blockIdx.y * 128;
  const int col0 = blockIdx.x * 128;
  const int tx = tid & 15, ty = tid >> 4;
  const int ar = tid >> 2;          // 0..63
  const int ac = (tid & 3) << 2;    // 0,4,8,12

  float acc[8][8];
  #pragma unroll
  for (int i = 0; i < 8; ++i)
    #pragma unroll
    for (int j = 0; j < 8; ++j) acc[i][j] = 0.f;

  const float* Ap0 = A + (size_t)(row0 + ar) * K + ac;
  const float* Ap1 = A + (size_t)(row0 + ar + 64) * K + ac;
  const float* Wp0 = W + (size_t)(col0 + ar) * K + ac;
  const float* Wp1 = W + (size_t)(col0 + ar + 64) * K + ac;

  float4 pa0 = *(const float4*)Ap0;
  float4 pa1 = *(const float4*)Ap1;
  float4 pw0 = *(const float4*)Wp0;
  float4 pw1 = *(const float4*)Wp1;
  As[0][ac+0][ar] = pa0.x; As[0][ac+1][ar] = pa0.y; As[0][ac+2][ar] = pa0.z; As[0][ac+3][ar] = pa0.w;
  As[0][ac+0][ar+64] = pa1.x; As[0][ac+1][ar+64] = pa1.y; As[0][ac+2][ar+64] = pa1.z; As[0][ac+3][ar+64] = pa1.w;
  Ws[0][ac+0][ar] = pw0.x; Ws[0][ac+1][ar] = pw0.y; Ws[0][ac+2][ar] = pw0.z; Ws[0][ac+3][ar] = pw0.w;
  Ws[0][ac+0][ar+64] = pw1.x; Ws[0][ac+1][ar+64] = pw1.y; Ws[0][ac+2][ar+64] = pw1.z; Ws[0][ac+3][ar+64] = pw1.w;
  __syncthreads();

  int buf = 0;
  for (int k0 = 0; k0 < K; k0 += 16) {
    const bool last = (k0 + 16 >= K);
    if (!last) {
      pa0 = *(const float4*)(Ap0 + k0 + 16);
      pa1 = *(const float4*)(Ap1 + k0 + 16);
      pw0 = *(const float4*)(Wp0 + k0 + 16);
      pw1 = *(const float4*)(Wp1 + k0 + 16);
    }
    #pragma unroll
    for (int kk = 0; kk < 16; ++kk) {   // ascending k — exact chain order
      float a[8], b[8];
      *(float4*)&a[0] = *(const float4*)&As[buf][kk][ty*4];
      *(float4*)&a[4] = *(const float4*)&As[buf][kk][64 + ty*4];
      *(float4*)&b[0] = *(const float4*)&Ws[buf][kk][tx*4];
      *(float4*)&b[4] = *(const float4*)&Ws[buf][kk][64 + tx*4];
      #pragma unroll
      for (int i = 0; i < 8; ++i)
        #pragma unroll
        for (int j = 0; j < 8; ++j)
          acc[i][j] = fmaf(a[i], b[j], acc[i][j]);
    }
    if (!last) {
      int nb = buf ^ 1;
      As[nb][ac+0][ar] = pa0.x; As[nb][ac+1][ar] = pa0.y; As[nb][ac+2][ar] = pa0.z; As[nb][ac+3][ar] = pa0.w;
      As[nb][ac+0][ar+64] = pa1.x; As[nb][ac+1][ar+64] = pa1.y; As[nb][ac+2][ar+64] = pa1.z; As[nb][ac+3][ar+64] = pa1.w;
      Ws[nb][ac+0][ar] = pw0.x; Ws[nb][ac+1][ar] = pw0.y; Ws[nb][ac+2][ar] = pw0.z; Ws[nb][ac+3][ar] = pw0.w;
      Ws[nb][ac+0][ar+64] = pw1.x; Ws[nb][ac+1][ar+64] = pw1.y; Ws[nb][ac+2][ar+64] = pw1.z; Ws[nb][ac+3][ar+64] = pw1.w;
      __syncthreads();
      buf = nb;
    }
  }

  #pragma unroll
  for (int ih = 0; ih < 2; ++ih)
    #pragma unroll
    for (int i = 0; i < 4; ++i) {
      size_t r = (size_t)(row0 + ih*64 + ty*4 + i);
      #pragma unroll
      for (int jh = 0; jh < 2; ++jh) {
        int c = col0 + jh*64 + tx*4;
        float4 o4;
        o4.x = acc[ih*4+i][jh*4+0] + bias[c+0];
        o4.y = acc[ih*4+i][jh*4+1] + bias[c+1];
        o4.z = acc[ih*4+i][jh*4+2] + bias[c+2];
        o4.w = acc[ih*4+i][jh*4+3] + bias[c+3];
        *(float4*)(Y + r * Nc + c) = o4;
      }
    }
}

// ---------------------------------------------------------------------------
// Sparse f2 GEMM over binary spikes with 4-WAY ROW INTERLEAVE for ILP.
// Per-row chain remains strictly ascending-k (LSB-pop within word, words in
// ascending chunk order) -> BIT-IDENTICAL to the dense reference chain
// (fmaf(0,w,acc)==acc; fmaf(1,w,acc)==acc+w in RN). Wave-uniform masks.
// ---------------------------------------------------------------------------
__global__ __launch_bounds__(256, 2)
void gemm_f32_f2sparse(const unsigned long long* __restrict__ hmask,
                       const float* __restrict__ W, const float* __restrict__ bias,
                       float* __restrict__ Y) {
  __shared__ float Ws[2][64][132];            // [k-in-chunk][col]
  __shared__ unsigned long long Ms[2][64];    // per-row mask word
  const int tid  = threadIdx.x;
  const int row0 = blockIdx.y * 64;
  const int col0 = blockIdx.x * 128;
  const int lane = tid & 63, wv = tid >> 6;   // 4 waves
  const int sc  = tid >> 1;                   // staging col 0..127
  const int skq = (tid & 1) * 32;             // staging k offset

  float acc[16][2];
  #pragma unroll
  for (int i = 0; i < 16; ++i) { acc[i][0] = 0.f; acc[i][1] = 0.f; }

  const float* Wp = W + (size_t)(col0 + sc) * 2048 + skq;

  #pragma unroll
  for (int i = 0; i < 8; ++i) {
    float4 w4 = *(const float4*)(Wp + 4*i);
    Ws[0][skq+4*i+0][sc] = w4.x; Ws[0][skq+4*i+1][sc] = w4.y;
    Ws[0][skq+4*i+2][sc] = w4.z; Ws[0][skq+4*i+3][sc] = w4.w;
  }
  if (tid < 64) Ms[0][tid] = hmask[(size_t)(row0 + tid) * 32];
  __syncthreads();

  int buf = 0;
  for (int ch = 0; ch < 32; ++ch) {
    const bool last = (ch == 31);
    float4 pw[8];
    unsigned long long pm = 0;
    if (!last) {
      #pragma unroll
      for (int i = 0; i < 8; ++i) pw[i] = *(const float4*)(Wp + (ch+1)*64 + 4*i);
      if (tid < 64) pm = hmask[(size_t)(row0 + tid) * 32 + ch + 1];
    }
    // 4-way interleaved walk: rows {g, g+4, g+8, g+12} — 4 independent
    // acc chains + 4 independent LDS loads per iteration (ILP ~4).
    #pragma unroll
    for (int g = 0; g < 4; ++g) {
      unsigned long long m0 = Ms[buf][wv*16 + g];
      unsigned long long m1 = Ms[buf][wv*16 + g + 4];
      unsigned long long m2 = Ms[buf][wv*16 + g + 8];
      unsigned long long m3 = Ms[buf][wv*16 + g + 12];
      while (m0 | m1 | m2 | m3) {           // wave-uniform
        if (m0) {
          int k = __builtin_ctzll(m0); m0 &= m0 - 1;
          float2 b2 = *(const float2*)&Ws[buf][k][lane*2];
          acc[g][0]    = acc[g][0]    + b2.x;     // ascending-k RN adds
          acc[g][1]    = acc[g][1]    + b2.y;
        }
        if (m1) {
          int k = __builtin_ctzll(m1); m1 &= m1 - 1;
          float2 b2 = *(const float2*)&Ws[buf][k][lane*2];
          acc[g+4][0]  = acc[g+4][0]  + b2.x;
          acc[g+4][1]  = acc[g+4][1]  + b2.y;
        }
        if (m2) {
          int k = __builtin_ctzll(m2); m2 &= m2 - 1;
          float2 b2 = *(const float2*)&Ws[buf][k][lane*2];
          acc[g+8][0]  = acc[g+8][0]  + b2.x;
          acc[g+8][1]  = acc[g+8][1]  + b2.y;
        }
        if (m3) {
          int k = __builtin_ctzll(m3); m3 &= m3 - 1;
          float2 b2 = *(const float2*)&Ws[buf][k][lane*2];
          acc[g+12][0] = acc[g+12][0] + b2.x;
          acc[g+12][1] = acc[g+12][1] + b2.y;
        }
      }
    }
    if (!last) {
      int nb = buf ^ 1;
      #pragma unroll
      for (int i = 0; i < 8; ++i) {
        Ws[nb][skq+4*i+0][sc] = pw[i].x; Ws[nb][skq+4*i+1][sc] = pw[i].y;
        Ws[nb][skq+4*i+2][sc] = pw[i].z; Ws[nb][skq+4*i+3][sc] = pw[i].w;
      }
      if (tid < 64) Ms[nb][tid] = pm;
      __syncthreads();
      buf = nb;
    }
  }

  #pragma unroll
  for (int ri = 0; ri < 16; ++ri) {
    size_t r = (size_t)(row0 + wv*16 + ri);
    int c = col0 + lane*2;
    float2 o2;
    o2.x = acc[ri][0] + bias[c+0];
    o2.y = acc[ri][1] + bias[c+1];
    *(float2*)(Y + r * 512 + c) = o2;
  }
}

// ---------------------------------------------------------------------------
// Fused q+k GEMM (R14-verbatim)
// ---------------------------------------------------------------------------
__global__ __launch_bounds__(256, 2)
void gemm_f32_qk(const float* __restrict__ A,
                 const float* __restrict__ Wq, const float* __restrict__ bq,
                 const float* __restrict__ Wk, const float* __restrict__ bk,
                 float* __restrict__ Yq, float* __restrict__ Yk,
                 int Nc, int K) {
  __shared__ float As[2][16][68];
  __shared__ float Wqs[2][16][132];
  __shared__ float Wks[2][16][132];
  const int tid  = threadIdx.x;
  const int row0 = blockIdx.y * 64;
  const int col0 = blockIdx.x * 128;
  const int tx = tid & 15, ty = tid >> 4;
  const int ar = tid >> 2;
  const int ac = (tid & 3) << 2;

  float accq[4][8], acck[4][8];
  #pragma unroll
  for (int i = 0; i < 4; ++i)
    #pragma unroll
    for (int j = 0; j < 8; ++j) { accq[i][j] = 0.f; acck[i][j] = 0.f; }

  const float* Ap   = A  + (size_t)(row0 + ar) * K + ac;
  const float* Wqp0 = Wq + (size_t)(col0 + ar) * K + ac;
  const float* Wqp1 = Wq + (size_t)(col0 + ar + 64) * K + ac;
  const float* Wkp0 = Wk + (size_t)(col0 + ar) * K + ac;
  const float* Wkp1 = Wk + (size_t)(col0 + ar + 64) * K + ac;

  float4 pa  = *(const float4*)Ap;
  float4 pq0 = *(const float4*)Wqp0;
  float4 pq1 = *(const float4*)Wqp1;
  float4 pk0 = *(const float4*)Wkp0;
  float4 pk1 = *(const float4*)Wkp1;
  As[0][ac+0][ar] = pa.x; As[0][ac+1][ar] = pa.y; As[0][ac+2][ar] = pa.z; As[0][ac+3][ar] = pa.w;
  Wqs[0][ac+0][ar] = pq0.x; Wqs[0][ac+1][ar] = pq0.y; Wqs[0][ac+2][ar] = pq0.z; Wqs[0][ac+3][ar] = pq0.w;
  Wqs[0][ac+0][ar+64] = pq1.x; Wqs[0][ac+1][ar+64] = pq1.y; Wqs[0][ac+2][ar+64] = pq1.z; Wqs[0][ac+3][ar+64] = pq1.w;
  Wks[0][ac+0][ar] = pk0.x; Wks[0][ac+1][ar] = pk0.y; Wks[0][ac+2][ar] = pk0.z; Wks[0][ac+3][ar] = pk0.w;
  Wks[0][ac+0][ar+64] = pk1.x; Wks[0][ac+1][ar+64] = pk1.y; Wks[0][ac+2][ar+64] = pk1.z; Wks[0][ac+3][ar+64] = pk1.w;
  __syncthreads();

  int buf = 0;
  for (int k0 = 0; k0 < K; k0 += 16) {
    const bool last = (k0 + 16 >= K);
    if (!last) {
      pa  = *(const float4*)(Ap   + k0 + 16);
      pq0 = *(const float4*)(Wqp0 + k0 + 16);
      pq1 = *(const float4*)(Wqp1 + k0 + 16);
      pk0 = *(const float4*)(Wkp0 + k0 + 16);
      pk1 = *(const float4*)(Wkp1 + k0 + 16);
    }
    #pragma unroll
    for (int kk = 0; kk < 16; ++kk) {
      float4 av = *(const float4*)&As[buf][kk][ty*4];
      float a[4] = {av.x, av.y, av.z, av.w};
      float b[8];
      *(float4*)&b[0] = *(const float4*)&Wqs[buf][kk][tx*4];
      *(float4*)&b[4] = *(const float4*)&Wqs[buf][kk][64 + tx*4];
      #pragma unroll
      for (int i = 0; i < 4; ++i)
        #pragma unroll
        for (int j = 0; j < 8; ++j)
          accq[i][j] = fmaf(a[i], b[j], accq[i][j]);
      *(float4*)&b[0] = *(const float4*)&Wks[buf][kk][tx*4];
      *(float4*)&b[4] = *(const float4*)&Wks[buf][kk][64 + tx*4];
      #pragma unroll
      for (int i = 0; i < 4; ++i)
        #pragma unroll
        for (int j = 0; j < 8; ++j)
          acck[i][j] = fmaf(a[i], b[j], acck[i][j]);
    }
    if (!last) {
      int nb = buf ^ 1;
      As[nb][ac+0][ar] = pa.x; As[nb][ac+1][ar] = pa.y; As[nb][ac+2][ar] = pa.z; As[nb][ac+3][ar] = pa.w;
      Wqs[nb][ac+0][ar] = pq0.x; Wqs[nb][ac+1][ar] = pq0.y; Wqs[nb][ac+2][ar] = pq0.z; Wqs[nb][ac+3][ar] = pq0.w;
      Wqs[nb][ac+0][ar+64] = pq1.x; Wqs[nb][ac+1][ar+64] = pq1.y; Wqs[nb][ac+2][ar+64] = pq1.z; Wqs[nb][ac+3][ar+64] = pq1.w;
      Wks[nb][ac+0][ar] = pk0.x; Wks[nb][ac+1][ar] = pk0.y; Wks[nb][ac+2][ar] = pk0.z; Wks[nb][ac+3][ar] = pk0.w;
      Wks[nb][ac+0][ar+64] = pk1.x; Wks[nb][ac+1][ar+64] = pk1.y; Wks[nb][ac+2][ar+64] = pk1.z; Wks[nb][ac+3][ar+64] = pk1.w;
      __syncthreads();
      buf = nb;
    }
  }

  #pragma unroll
  for (int i = 0; i < 4; ++i) {
    size_t r = (size_t)(row0 + ty*4 + i);
    #pragma unroll
    for (int jh = 0; jh < 2; ++jh) {
      int c = col0 + jh*64 + tx*4;
      float4 oq, ok;
      oq.x = accq[i][jh*4+0] + bq[c+0];
      oq.y = accq[i][jh*4+1] + bq[c+1];
      oq.z = accq[i][jh*4+2] + bq[c+2];
      oq.w = accq[i][jh*4+3] + bq[c+3];
      *(float4*)(Yq + r * Nc + c) = oq;
      ok.x = acck[i][jh*4+0] + bk[c+0];
      ok.y = acck[i][jh*4+1] + bk[c+1];
      ok.z = acck[i][jh*4+2] + bk[c+2];
      ok.w = acck[i][jh*4+3] + bk[c+3];
      *(float4*)(Yk + r * Nc + c) = ok;
    }
  }
}

// ---------------------------------------------------------------------------
// v/p GEMM v4 (R17-verbatim, proven): f32 LDS, cvt->f64 at fragment read,
// same ascending-k f64 chain as R9 -> bit-identical outputs.
// ---------------------------------------------------------------------------
__global__ __launch_bounds__(256, 2)
void gemm_f64_v4(const float* __restrict__ A, const float* __restrict__ W,
                 const float* __restrict__ bias, float* __restrict__ Y,
                 int Nc, int K) {
  __shared__ float As[2][16][68];
  __shared__ float Ws[2][16][132];
  const int tid  = threadIdx.x;
  const int row0 = blockIdx.y * 64;
  const int col0 = blockIdx.x * 128;
  const int tx = tid & 15, ty = tid >> 4;
  const int ar = tid >> 2;
  const int ac = (tid & 3) << 2;

  double acc[4][8];
  #pragma unroll
  for (int i = 0; i < 4; ++i)
    #pragma unroll
    for (int j = 0; j < 8; ++j) acc[i][j] = 0.0;

  const float* Ap  = A + (size_t)(row0 + ar) * K + ac;
  const float* Wp0 = W + (size_t)(col0 + ar) * K + ac;
  const float* Wp1 = W + (size_t)(col0 + ar + 64) * K + ac;

  float4 pa  = *(const float4*)Ap;
  float4 pw0 = *(const float4*)Wp0;
  float4 pw1 = *(const float4*)Wp1;
  As[0][ac+0][ar] = pa.x; As[0][ac+1][ar] = pa.y; As[0][ac+2][ar] = pa.z; As[0][ac+3][ar] = pa.w;
  Ws[0][ac+0][ar] = pw0.x; Ws[0][ac+1][ar] = pw0.y; Ws[0][ac+2][ar] = pw0.z; Ws[0][ac+3][ar] = pw0.w;
  Ws[0][ac+0][ar+64] = pw1.x; Ws[0][ac+1][ar+64] = pw1.y; Ws[0][ac+2][ar+64] = pw1.z; Ws[0][ac+3][ar+64] = pw1.w;
  __syncthreads();

  int buf = 0;
  for (int k0 = 0; k0 < K; k0 += 16) {
    const bool last = (k0 + 16 >= K);
    if (!last) {
      pa  = *(const float4*)(Ap  + k0 + 16);
      pw0 = *(const float4*)(Wp0 + k0 + 16);
      pw1 = *(const float4*)(Wp1 + k0 + 16);
    }
    #pragma unroll
    for (int kk = 0; kk < 16; ++kk) {   // ascending k — exact chain order
      float4 av  = *(const float4*)&As[buf][kk][ty*4];
      float4 bv0 = *(const float4*)&Ws[buf][kk][tx*4];
      float4 bv1 = *(const float4*)&Ws[buf][kk][64 + tx*4];
      double a[4] = {(double)av.x, (double)av.y, (double)av.z, (double)av.w};
      double b[8] = {(double)bv0.x, (double)bv0.y, (double)bv0.z, (double)bv0.w,
                     (double)bv1.x, (double)bv1.y, (double)bv1.z, (double)bv1.w};
      #pragma unroll
      for (int i = 0; i < 4; ++i)
        #pragma unroll
        for (int j = 0; j < 8; ++j)
          acc[i][j] = fma(a[i], b[j], acc[i][j]);
    }
    if (!last) {
      int nb = buf ^ 1;
      As[nb][ac+0][ar] = pa.x; As[nb][ac+1][ar] = pa.y; As[nb][ac+2][ar] = pa.z; As[nb][ac+3][ar] = pa.w;
      Ws[nb][ac+0][ar] = pw0.x; Ws[nb][ac+1][ar] = pw0.y; Ws[nb][ac+2][ar] = pw0.z; Ws[nb][ac+3][ar] = pw0.w;
      Ws[nb][ac+0][ar+64] = pw1.x; Ws[nb][ac+1][ar+64] = pw1.y; Ws[nb][ac+2][ar+64] = pw1.z; Ws[nb][ac+3][ar+64] = pw1.w;
      __syncthreads();
      buf = nb;
    }
  }

  #pragma unroll
  for (int i = 0; i < 4; ++i) {
    size_t r = (size_t)(row0 + ty*4 + i);
    #pragma unroll
    for (int jh = 0; jh < 2; ++jh) {
      int c = col0 + jh*64 + tx*4;
      float4 o4;
      o4.x = (float)(acc[i][jh*4+0] + (double)bias[c+0]);
      o4.y = (float)(acc[i][jh*4+1] + (double)bias[c+1]);
      o4.z = (float)(acc[i][jh*4+2] + (double)bias[c+2]);
      o4.w = (float)(acc[i][jh*4+3] + (double)bias[c+3]);
      *(float4*)(Y + r * Nc + c) = o4;
    }
  }
}

// ---------------------------------------------------------------------------
// BN stats stage 1 (R1-verbatim)
// ---------------------------------------------------------------------------
__global__ __launch_bounds__(256)
void col_stats_partial(const float* __restrict__ Y, int Nc,
                       float* __restrict__ psum, float* __restrict__ psq) {
  const int r0 = blockIdx.x * 32;
  for (int c = threadIdx.x; c < Nc; c += 256) {
    float s = 0.f, q = 0.f;
    const float* p = Y + (size_t)r0 * Nc + c;
    for (int r = 0; r < 32; ++r) {
      float v = p[(size_t)r * Nc];
      s += v;
      q = fmaf(v, v, q);
    }
    psum[(size_t)blockIdx.x * Nc + c] = s;
    psq [(size_t)blockIdx.x * Nc + c] = q;
  }
}

// stage 2 (R1-verbatim)
__global__ void col_stats_final(const float* __restrict__ psum, const float* __restrict__ psq,
                                int Nc, const float* __restrict__ g, const float* __restrict__ beta,
                                float* __restrict__ chp) {
  int c = blockIdx.x * blockDim.x + threadIdx.x;
  if (c >= Nc) return;
  double s = 0.0, q = 0.0;
  for (int p = 0; p < 512; ++p) {
    s += (double)psum[(size_t)p * Nc + c];
    q += (double)psq [(size_t)p * Nc + c];
  }
  double mean = s / (double)M_;
  double var  = q / (double)M_ - mean * mean;
  float alpha = g[c] / sqrtf((float)var + 1e-5f);
  chp[2*c]   = alpha;
  chp[2*c+1] = fmaf(-(float)mean, alpha, beta[c]);
}

// stage 2 for v/p paths (R9-verbatim)
__global__ void col_stats_final_f64(const float* __restrict__ psum, const float* __restrict__ psq,
                                    int Nc, const float* __restrict__ g, const float* __restrict__ beta,
                                    double* __restrict__ chpd) {
  int c = blockIdx.x * blockDim.x + threadIdx.x;
  if (c >= Nc) return;
  double s = 0.0, q = 0.0;
  for (int p = 0; p < 512; ++p) {
    s += (double)psum[(size_t)p * Nc + c];
    q += (double)psq [(size_t)p * Nc + c];
  }
  double mean = s / (double)M_;
  double var  = q / (double)M_ - mean * mean;
  double alpha = (double)g[c] / sqrt(var + 1e-5);
  chpd[2*c]   = alpha;
  chpd[2*c+1] = (double)beta[c] - mean * alpha;
}

// ---------------------------------------------------------------------------
// BN + LIF masks (R1-verbatim) — q/k decisions, frozen
// ---------------------------------------------------------------------------
__global__ __launch_bounds__(256)
void bnlif_mask(const float* __restrict__ Y, const float* __restrict__ chp,
                unsigned long long* __restrict__ mask) {
  int lane = threadIdx.x & 63;
  int u  = blockIdx.x * 4 + (threadIdx.x >> 6);
  int bn = u >> 3, cg = u & 7;
  int c  = cg * 64 + lane;
  float alpha = chp[2*c], bb = chp[2*c+1];
  float v = 0.f;
  #pragma unroll
  for (int t = 0; t < 4; ++t) {
    float y  = Y[((size_t)(t * BNP_ + bn)) * C_ + c];
    float uu = fmaf(y, alpha, bb);
    v = v + (uu - v) * 0.5f;
    bool sp = (v >= 1.0f);
    unsigned long long m = __ballot(sp);
    if (sp) v = 0.f;
    if (lane == 0) mask[((size_t)(t * BNP_ + bn)) * H_ + cg] = m;
  }
}

// xo = x + BN(Yp) (R9-verbatim)
__global__ void bn_residual_f64(const float* __restrict__ Y, const double* __restrict__ chpd,
                                const float* __restrict__ x, float* __restrict__ out) {
  const long total4 = (long)M_ * C_ / 4;
  for (long i = (long)blockIdx.x * blockDim.x + threadIdx.x; i < total4;
       i += (long)gridDim.x * blockDim.x) {
    int c4 = (int)(i & (C_/4 - 1)) * 4;
    float4 y = ((const float4*)Y)[i];
    float4 xv = ((const float4*)x)[i];
    float4 r;
    r.x = (float)((double)xv.x + fma((double)y.x, chpd[2*(c4+0)], chpd[2*(c4+0)+1]));
    r.y = (float)((double)xv.y + fma((double)y.y, chpd[2*(c4+1)], chpd[2*(c4+1)+1]));
    r.z = (float)((double)xv.z + fma((double)y.z, chpd[2*(c4+2)], chpd[2*(c4+2)+1]));
    r.w = (float)((double)xv.w + fma((double)y.w, chpd[2*(c4+3)], chpd[2*(c4+3)+1]));
    ((float4*)out)[i] = r;
  }
}

// BN + LIF for f1 -> 64-bit spike masks per row (R15-verbatim)
__global__ __launch_bounds__(256)
void bnlif_hmask(const float* __restrict__ Y, const float* __restrict__ chp,
                 unsigned long long* __restrict__ hmask) {
  int c  = blockIdx.x * 256 + threadIdx.x;   // < 2048
  int bn = blockIdx.y;
  int lane = threadIdx.x & 63;
  int word = blockIdx.x * 4 + (threadIdx.x >> 6);
  float alpha = chp[2*c], bb = chp[2*c+1];
  float v = 0.f;
  #pragma unroll
  for (int t = 0; t < 4; ++t) {
    size_t row = (size_t)(t * BNP_ + bn);
    float uu = fmaf(Y[row * HID_ + c], alpha, bb);
    v = v + (uu - v) * 0.5f;
    bool sp = (v >= 1.f);
    unsigned long long m = __ballot(sp);
    if (sp) v = 0.f;
    if (lane == 0) hmask[row * 32 + word] = m;
  }
}

// BN + LIF for f2 + final residual (R1-verbatim)
__global__ __launch_bounds__(256)
void bnlif_final(const float* __restrict__ Y, const float* __restrict__ chp,
                 const float* __restrict__ xo, float* __restrict__ out) {
  int c  = blockIdx.x * 256 + threadIdx.x;   // < 512
  int bn = blockIdx.y;
  float alpha = chp[2*c], bb = chp[2*c+1];
  float v = 0.f;
  #pragma unroll
  for (int t = 0; t < 4; ++t) {
    size_t idx = ((size_t)(t * BNP_ + bn)) * C_ + c;
    float uu = fmaf(Y[idx], alpha, bb);
    v = v + (uu - v) * 0.5f;
    bool sp = (v >= 1.f);
    out[idx] = xo[idx] + (sp ? 1.f : 0.f);
    if (sp) v = 0.f;
  }
}

// ---------------------------------------------------------------------------
// Attention with fused BN(v) at V-load (R17-verbatim, proven)
// ---------------------------------------------------------------------------
__global__ __launch_bounds__(256)
void attn_kernel_f64(const unsigned long long* __restrict__ qmask,
                     const unsigned long long* __restrict__ kmask,
                     const float* __restrict__ vraw, const double* __restrict__ chpd,
                     float* __restrict__ o) {
  __shared__ unsigned long long km[256];
  __shared__ float vt[256][64];
  int rb  = blockIdx.x & 3;
  int tbh = blockIdx.x >> 2;
  int h   = tbh & 7, tb = tbh >> 3;
  int tid = threadIdx.x;

  km[tid] = kmask[(size_t)(tb * 256 + tid) * H_ + h];
  const float* vbase = vraw + (size_t)tb * 256 * C_ + h * 64;
  #pragma unroll
  for (int i = 0; i < 16; ++i) {
    int f = i * 256 + tid;
    int r = f >> 4, c4 = f & 15;
    float4 y = *(const float4*)(vbase + (size_t)r * C_ + c4 * 4);
    int ch = h * 64 + c4 * 4;
    vt[r][c4*4+0] = (float)fma((double)y.x, chpd[2*(ch+0)], chpd[2*(ch+0)+1]);
    vt[r][c4*4+1] = (float)fma((double)y.y, chpd[2*(ch+1)], chpd[2*(ch+1)+1]);
    vt[r][c4*4+2] = (float)fma((double)y.z, chpd[2*(ch+2)], chpd[2*(ch+2)+1]);
    vt[r][c4*4+3] = (float)fma((double)y.w, chpd[2*(ch+3)], chpd[2*(ch+3)+1]);
  }
  int lane = tid & 63, w = tid >> 6;
  int nr = lane & 15, dg = lane >> 4;
  int n  = rb * 64 + w * 16 + nr;
  unsigned long long qm = qmask[(size_t)(tb * 256 + n) * H_ + h];
  __syncthreads();

  double acc[16];
  #pragma unroll
  for (int j = 0; j < 16; ++j) acc[j] = 0.0;

  for (int m = 0; m < 256; ++m) {
    double s = (double)__popcll(qm & km[m]) * 0.125;
    #pragma unroll
    for (int j = 0; j < 4; ++j) {
      float4 vv = *(const float4*)&vt[m][dg * 16 + j * 4];
      acc[j*4+0] = fma(s, (double)vv.x, acc[j*4+0]);
      acc[j*4+1] = fma(s, (double)vv.y, acc[j*4+1]);
      acc[j*4+2] = fma(s, (double)vv.z, acc[j*4+2]);
      acc[j*4+3] = fma(s, (double)vv.w, acc[j*4+3]);
    }
  }
  float* orow = o + (size_t)(tb * 256 + n) * C_ + h * 64 + dg * 16;
  #pragma unroll
  for (int j = 0; j < 4; ++j)
    *(float4*)(orow + j * 4) = make_float4((float)acc[j*4], (float)acc[j*4+1],
                                           (float)acc[j*4+2], (float)acc[j*4+3]);
}

// ---------------------------------------------------------------------------
extern "C" void kernel_launch(void* const* d_in, const int* in_sizes, int n_in,
                              void* d_out, int out_size, void* d_ws, size_t ws_size,
                              hipStream_t stream) {
  const float* x    = (const float*)d_in[0];
  const float* qw   = (const float*)d_in[2];
  const float* qb   = (const float*)d_in[3];
  const float* qg   = (const float*)d_in[4];
  const float* qbe  = (const float*)d_in[5];
  const float* kw   = (const float*)d_in[6];
  const float* kb   = (const float*)d_in[7];
  const float* kg   = (const float*)d_in[8];
  const float* kbe  = (const float*)d_in[9];
  const float* vw   = (const float*)d_in[10];
  const float* vb   = (const float*)d_in[11];
  const float* vg   = (const float*)d_in[12];
  const float* vbe  = (const float*)d_in[13];
  const float* pw   = (const float*)d_in[14];
  const float* pb   = (const float*)d_in[15];
  const float* pg   = (const float*)d_in[16];
  const float* pbe  = (const float*)d_in[17];
  const float* f1w  = (const float*)d_in[18];
  const float* f1b  = (const float*)d_in[19];
  const float* f1g  = (const float*)d_in[20];
  const float* f1be = (const float*)d_in[21];
  const float* f2w  = (const float*)d_in[22];
  const float* f2b  = (const float*)d_in[23];
  const float* f2g  = (const float*)d_in[24];
  const float* f2be = (const float*)d_in[25];

  char* ws = (char*)d_ws;
  float* bufY = (float*)(ws);                                   // 128 MB
  float* bufK = bufY + 8388608;                                 // k at bufY+32MB
  float* bufV = (float*)(ws + 134217728ull);                    //  32 MB (hmask home)
  float* bufO = (float*)(ws + 167772160ull);                    //  32 MB (o, then xo)
  unsigned long long* qmask = (unsigned long long*)(ws + 201326592ull);
  unsigned long long* kmask = (unsigned long long*)(ws + 202375168ull);
  float* psum = (float*)(ws + 203423744ull);                    // 4 MB
  float* psq  = (float*)(ws + 207618048ull);                    // 4 MB
  float* chp  = (float*)(ws + 211812352ull);                    // 16 KB
  double* chpd = (double*)(ws + 211828736ull);                  // 8 KB
  unsigned long long* hmask = (unsigned long long*)bufV;        // 4 MB

  float* out = (float*)d_out;

  // ---- fused q+k GEMM ----
  gemm_f32_qk<<<dim3(4,256), 256, 0, stream>>>(x, qw, qb, kw, kb, bufY, bufK, C_, C_);
  col_stats_partial<<<512, 256, 0, stream>>>(bufY, C_, psum, psq);
  col_stats_final<<<2, 256, 0, stream>>>(psum, psq, C_, qg, qbe, chp);
  bnlif_mask<<<8192, 256, 0, stream>>>(bufY, chp, qmask);
  col_stats_partial<<<512, 256, 0, stream>>>(bufK, C_, psum, psq);
  col_stats_final<<<2, 256, 0, stream>>>(psum, psq, C_, kg, kbe, chp);
  bnlif_mask<<<8192, 256, 0, stream>>>(bufK, chp, kmask);
  // ---- v path (f64 acc, f32 LDS) ----
  gemm_f64_v4<<<dim3(4,256), 256, 0, stream>>>(x, vw, vb, bufY, C_, C_);
  col_stats_partial<<<512, 256, 0, stream>>>(bufY, C_, psum, psq);
  col_stats_final_f64<<<2, 256, 0, stream>>>(psum, psq, C_, vg, vbe, chpd);
  // ---- attention (BN(v) fused at V-load) ----
  attn_kernel_f64<<<2048, 256, 0, stream>>>(qmask, kmask, bufY, chpd, bufO);
  // ---- projection + residual ----
  gemm_f64_v4<<<dim3(4,256), 256, 0, stream>>>(bufO, pw, pb, bufY, C_, C_);
  col_stats_partial<<<512, 256, 0, stream>>>(bufY, C_, psum, psq);
  col_stats_final_f64<<<2, 256, 0, stream>>>(psum, psq, C_, pg, pbe, chpd);
  bn_residual_f64<<<2048, 256, 0, stream>>>(bufY, chpd, x, bufO);
  // ---- MLP f1 (proven 128x128 tile) ----
  gemm_f32_t128<<<dim3(16,128), 256, 0, stream>>>(bufO, f1w, f1b, bufY, HID_, C_);
  col_stats_partial<<<512, 256, 0, stream>>>(bufY, HID_, psum, psq);
  col_stats_final<<<8, 256, 0, stream>>>(psum, psq, HID_, f1g, f1be, chp);
  bnlif_hmask<<<dim3(8,4096), 256, 0, stream>>>(bufY, chp, hmask);
  // ---- MLP f2: SPARSE over spike masks, 4-way row-interleaved walk ----
  gemm_f32_f2sparse<<<dim3(4,256), 256, 0, stream>>>(hmask, f2w, f2b, bufY);
  col_stats_partial<<<512, 256, 0, stream>>>(bufY, C_, psum, psq);
  col_stats_final<<<2, 256, 0, stream>>>(psum, psq, C_, f2g, f2be, chp);
  bnlif_final<<<dim3(2,4096), 256, 0, stream>>>(bufY, chp, bufO, out);
}

// Round 20
// 1772.781 us; speedup vs baseline: 1.4255x; 1.4255x over previous
//
#include <hip/hip_runtime.h>
#include <cstdint>

#define T_ 4
#define B_ 16
#define N_ 256
#define C_ 512
#define H_ 8
#define HID_ 2048
#define M_ (T_*B_*N_)      // 16384 rows
#define BNP_ (B_*N_)       // 4096 (b,n) pairs

// ---------------------------------------------------------------------------
// f32 GEMM, 128x128 tile, 8x8 micro, double-buffered, conflict-free fragment
// map. BIT-IDENTICAL per-element math to R1. Used for f1. (R16-verbatim)
// ---------------------------------------------------------------------------
__global__ __launch_bounds__(256, 2)
void gemm_f32_t128(const float* __restrict__ A, const float* __restrict__ W,
                   const float* __restrict__ bias, float* __restrict__ Y,
                   int Nc, int K) {
  __shared__ float As[2][16][132];
  __shared__ float Ws[2][16][132];
  const int tid  = threadIdx.x;
  const int row0 = blockIdx.y * 128;
  const int col0 = blockIdx.x * 128;
  const int tx = tid & 15, ty = tid >> 4;
  const int ar = tid >> 2;          // 0..63
  const int ac = (tid & 3) << 2;    // 0,4,8,12

  float acc[8][8];
  #pragma unroll
  for (int i = 0; i < 8; ++i)
    #pragma unroll
    for (int j = 0; j < 8; ++j) acc[i][j] = 0.f;

  const float* Ap0 = A + (size_t)(row0 + ar) * K + ac;
  const float* Ap1 = A + (size_t)(row0 + ar + 64) * K + ac;
  const float* Wp0 = W + (size_t)(col0 + ar) * K + ac;
  const float* Wp1 = W + (size_t)(col0 + ar + 64) * K + ac;

  float4 pa0 = *(const float4*)Ap0;
  float4 pa1 = *(const float4*)Ap1;
  float4 pw0 = *(const float4*)Wp0;
  float4 pw1 = *(const float4*)Wp1;
  As[0][ac+0][ar] = pa0.x; As[0][ac+1][ar] = pa0.y; As[0][ac+2][ar] = pa0.z; As[0][ac+3][ar] = pa0.w;
  As[0][ac+0][ar+64] = pa1.x; As[0][ac+1][ar+64] = pa1.y; As[0][ac+2][ar+64] = pa1.z; As[0][ac+3][ar+64] = pa1.w;
  Ws[0][ac+0][ar] = pw0.x; Ws[0][ac+1][ar] = pw0.y; Ws[0][ac+2][ar] = pw0.z; Ws[0][ac+3][ar] = pw0.w;
  Ws[0][ac+0][ar+64] = pw1.x; Ws[0][ac+1][ar+64] = pw1.y; Ws[0][ac+2][ar+64] = pw1.z; Ws[0][ac+3][ar+64] = pw1.w;
  __syncthreads();

  int buf = 0;
  for (int k0 = 0; k0 < K; k0 += 16) {
    const bool last = (k0 + 16 >= K);
    if (!last) {
      pa0 = *(const float4*)(Ap0 + k0 + 16);
      pa1 = *(const float4*)(Ap1 + k0 + 16);
      pw0 = *(const float4*)(Wp0 + k0 + 16);
      pw1 = *(const float4*)(Wp1 + k0 + 16);
    }
    #pragma unroll
    for (int kk = 0; kk < 16; ++kk) {   // ascending k — exact chain order
      float a[8], b[8];
      *(float4*)&a[0] = *(const float4*)&As[buf][kk][ty*4];
      *(float4*)&a[4] = *(const float4*)&As[buf][kk][64 + ty*4];
      *(float4*)&b[0] = *(const float4*)&Ws[buf][kk][tx*4];
      *(float4*)&b[4] = *(const float4*)&Ws[buf][kk][64 + tx*4];
      #pragma unroll
      for (int i = 0; i < 8; ++i)
        #pragma unroll
        for (int j = 0; j < 8; ++j)
          acc[i][j] = fmaf(a[i], b[j], acc[i][j]);
    }
    if (!last) {
      int nb = buf ^ 1;
      As[nb][ac+0][ar] = pa0.x; As[nb][ac+1][ar] = pa0.y; As[nb][ac+2][ar] = pa0.z; As[nb][ac+3][ar] = pa0.w;
      As[nb][ac+0][ar+64] = pa1.x; As[nb][ac+1][ar+64] = pa1.y; As[nb][ac+2][ar+64] = pa1.z; As[nb][ac+3][ar+64] = pa1.w;
      Ws[nb][ac+0][ar] = pw0.x; Ws[nb][ac+1][ar] = pw0.y; Ws[nb][ac+2][ar] = pw0.z; Ws[nb][ac+3][ar] = pw0.w;
      Ws[nb][ac+0][ar+64] = pw1.x; Ws[nb][ac+1][ar+64] = pw1.y; Ws[nb][ac+2][ar+64] = pw1.z; Ws[nb][ac+3][ar+64] = pw1.w;
      __syncthreads();
      buf = nb;
    }
  }

  #pragma unroll
  for (int ih = 0; ih < 2; ++ih)
    #pragma unroll
    for (int i = 0; i < 4; ++i) {
      size_t r = (size_t)(row0 + ih*64 + ty*4 + i);
      #pragma unroll
      for (int jh = 0; jh < 2; ++jh) {
        int c = col0 + jh*64 + tx*4;
        float4 o4;
        o4.x = acc[ih*4+i][jh*4+0] + bias[c+0];
        o4.y = acc[ih*4+i][jh*4+1] + bias[c+1];
        o4.z = acc[ih*4+i][jh*4+2] + bias[c+2];
        o4.w = acc[ih*4+i][jh*4+3] + bias[c+3];
        *(float4*)(Y + r * Nc + c) = o4;
      }
    }
}

// ---------------------------------------------------------------------------
// Sparse f2 GEMM over binary spikes (R15/R16/R18-verbatim, validated
// bit-identical, no spill): fmaf(0,w,acc)==acc; fmaf(1,w,acc)==acc+w in RN.
// ---------------------------------------------------------------------------
__global__ __launch_bounds__(256, 2)
void gemm_f32_f2sparse(const unsigned long long* __restrict__ hmask,
                       const float* __restrict__ W, const float* __restrict__ bias,
                       float* __restrict__ Y) {
  __shared__ float Ws[2][64][132];            // [k-in-chunk][col]
  __shared__ unsigned long long Ms[2][64];    // per-row mask word
  const int tid  = threadIdx.x;
  const int row0 = blockIdx.y * 64;
  const int col0 = blockIdx.x * 128;
  const int lane = tid & 63, wv = tid >> 6;   // 4 waves
  const int sc  = tid >> 1;                   // staging col 0..127
  const int skq = (tid & 1) * 32;             // staging k offset

  float acc[16][2];
  #pragma unroll
  for (int i = 0; i < 16; ++i) { acc[i][0] = 0.f; acc[i][1] = 0.f; }

  const float* Wp = W + (size_t)(col0 + sc) * 2048 + skq;

  #pragma unroll
  for (int i = 0; i < 8; ++i) {
    float4 w4 = *(const float4*)(Wp + 4*i);
    Ws[0][skq+4*i+0][sc] = w4.x; Ws[0][skq+4*i+1][sc] = w4.y;
    Ws[0][skq+4*i+2][sc] = w4.z; Ws[0][skq+4*i+3][sc] = w4.w;
  }
  if (tid < 64) Ms[0][tid] = hmask[(size_t)(row0 + tid) * 32];
  __syncthreads();

  int buf = 0;
  for (int ch = 0; ch < 32; ++ch) {
    const bool last = (ch == 31);
    float4 pw[8];
    unsigned long long pm = 0;
    if (!last) {
      #pragma unroll
      for (int i = 0; i < 8; ++i) pw[i] = *(const float4*)(Wp + (ch+1)*64 + 4*i);
      if (tid < 64) pm = hmask[(size_t)(row0 + tid) * 32 + ch + 1];
    }
    #pragma unroll
    for (int ri = 0; ri < 16; ++ri) {
      unsigned long long m = Ms[buf][wv*16 + ri];   // uniform across the wave
      while (m) {
        int k = __builtin_ctzll(m);
        m &= m - 1;
        float2 b2 = *(const float2*)&Ws[buf][k][lane*2];
        acc[ri][0] = acc[ri][0] + b2.x;   // plain RN adds, ascending k
        acc[ri][1] = acc[ri][1] + b2.y;
      }
    }
    if (!last) {
      int nb = buf ^ 1;
      #pragma unroll
      for (int i = 0; i < 8; ++i) {
        Ws[nb][skq+4*i+0][sc] = pw[i].x; Ws[nb][skq+4*i+1][sc] = pw[i].y;
        Ws[nb][skq+4*i+2][sc] = pw[i].z; Ws[nb][skq+4*i+3][sc] = pw[i].w;
      }
      if (tid < 64) Ms[nb][tid] = pm;
      __syncthreads();
      buf = nb;
    }
  }

  #pragma unroll
  for (int ri = 0; ri < 16; ++ri) {
    size_t r = (size_t)(row0 + wv*16 + ri);
    int c = col0 + lane*2;
    float2 o2;
    o2.x = acc[ri][0] + bias[c+0];
    o2.y = acc[ri][1] + bias[c+1];
    *(float2*)(Y + r * 512 + c) = o2;
  }
}

// ---------------------------------------------------------------------------
// Fused q+k GEMM (R14-verbatim)
// ---------------------------------------------------------------------------
__global__ __launch_bounds__(256, 2)
void gemm_f32_qk(const float* __restrict__ A,
                 const float* __restrict__ Wq, const float* __restrict__ bq,
                 const float* __restrict__ Wk, const float* __restrict__ bk,
                 float* __restrict__ Yq, float* __restrict__ Yk,
                 int Nc, int K) {
  __shared__ float As[2][16][68];
  __shared__ float Wqs[2][16][132];
  __shared__ float Wks[2][16][132];
  const int tid  = threadIdx.x;
  const int row0 = blockIdx.y * 64;
  const int col0 = blockIdx.x * 128;
  const int tx = tid & 15, ty = tid >> 4;
  const int ar = tid >> 2;
  const int ac = (tid & 3) << 2;

  float accq[4][8], acck[4][8];
  #pragma unroll
  for (int i = 0; i < 4; ++i)
    #pragma unroll
    for (int j = 0; j < 8; ++j) { accq[i][j] = 0.f; acck[i][j] = 0.f; }

  const float* Ap   = A  + (size_t)(row0 + ar) * K + ac;
  const float* Wqp0 = Wq + (size_t)(col0 + ar) * K + ac;
  const float* Wqp1 = Wq + (size_t)(col0 + ar + 64) * K + ac;
  const float* Wkp0 = Wk + (size_t)(col0 + ar) * K + ac;
  const float* Wkp1 = Wk + (size_t)(col0 + ar + 64) * K + ac;

  float4 pa  = *(const float4*)Ap;
  float4 pq0 = *(const float4*)Wqp0;
  float4 pq1 = *(const float4*)Wqp1;
  float4 pk0 = *(const float4*)Wkp0;
  float4 pk1 = *(const float4*)Wkp1;
  As[0][ac+0][ar] = pa.x; As[0][ac+1][ar] = pa.y; As[0][ac+2][ar] = pa.z; As[0][ac+3][ar] = pa.w;
  Wqs[0][ac+0][ar] = pq0.x; Wqs[0][ac+1][ar] = pq0.y; Wqs[0][ac+2][ar] = pq0.z; Wqs[0][ac+3][ar] = pq0.w;
  Wqs[0][ac+0][ar+64] = pq1.x; Wqs[0][ac+1][ar+64] = pq1.y; Wqs[0][ac+2][ar+64] = pq1.z; Wqs[0][ac+3][ar+64] = pq1.w;
  Wks[0][ac+0][ar] = pk0.x; Wks[0][ac+1][ar] = pk0.y; Wks[0][ac+2][ar] = pk0.z; Wks[0][ac+3][ar] = pk0.w;
  Wks[0][ac+0][ar+64] = pk1.x; Wks[0][ac+1][ar+64] = pk1.y; Wks[0][ac+2][ar+64] = pk1.z; Wks[0][ac+3][ar+64] = pk1.w;
  __syncthreads();

  int buf = 0;
  for (int k0 = 0; k0 < K; k0 += 16) {
    const bool last = (k0 + 16 >= K);
    if (!last) {
      pa  = *(const float4*)(Ap   + k0 + 16);
      pq0 = *(const float4*)(Wqp0 + k0 + 16);
      pq1 = *(const float4*)(Wqp1 + k0 + 16);
      pk0 = *(const float4*)(Wkp0 + k0 + 16);
      pk1 = *(const float4*)(Wkp1 + k0 + 16);
    }
    #pragma unroll
    for (int kk = 0; kk < 16; ++kk) {
      float4 av = *(const float4*)&As[buf][kk][ty*4];
      float a[4] = {av.x, av.y, av.z, av.w};
      float b[8];
      *(float4*)&b[0] = *(const float4*)&Wqs[buf][kk][tx*4];
      *(float4*)&b[4] = *(const float4*)&Wqs[buf][kk][64 + tx*4];
      #pragma unroll
      for (int i = 0; i < 4; ++i)
        #pragma unroll
        for (int j = 0; j < 8; ++j)
          accq[i][j] = fmaf(a[i], b[j], accq[i][j]);
      *(float4*)&b[0] = *(const float4*)&Wks[buf][kk][tx*4];
      *(float4*)&b[4] = *(const float4*)&Wks[buf][kk][64 + tx*4];
      #pragma unroll
      for (int i = 0; i < 4; ++i)
        #pragma unroll
        for (int j = 0; j < 8; ++j)
          acck[i][j] = fmaf(a[i], b[j], acck[i][j]);
    }
    if (!last) {
      int nb = buf ^ 1;
      As[nb][ac+0][ar] = pa.x; As[nb][ac+1][ar] = pa.y; As[nb][ac+2][ar] = pa.z; As[nb][ac+3][ar] = pa.w;
      Wqs[nb][ac+0][ar] = pq0.x; Wqs[nb][ac+1][ar] = pq0.y; Wqs[nb][ac+2][ar] = pq0.z; Wqs[nb][ac+3][ar] = pq0.w;
      Wqs[nb][ac+0][ar+64] = pq1.x; Wqs[nb][ac+1][ar+64] = pq1.y; Wqs[nb][ac+2][ar+64] = pq1.z; Wqs[nb][ac+3][ar+64] = pq1.w;
      Wks[nb][ac+0][ar] = pk0.x; Wks[nb][ac+1][ar] = pk0.y; Wks[nb][ac+2][ar] = pk0.z; Wks[nb][ac+3][ar] = pk0.w;
      Wks[nb][ac+0][ar+64] = pk1.x; Wks[nb][ac+1][ar+64] = pk1.y; Wks[nb][ac+2][ar+64] = pk1.z; Wks[nb][ac+3][ar+64] = pk1.w;
      __syncthreads();
      buf = nb;
    }
  }

  #pragma unroll
  for (int i = 0; i < 4; ++i) {
    size_t r = (size_t)(row0 + ty*4 + i);
    #pragma unroll
    for (int jh = 0; jh < 2; ++jh) {
      int c = col0 + jh*64 + tx*4;
      float4 oq, ok;
      oq.x = accq[i][jh*4+0] + bq[c+0];
      oq.y = accq[i][jh*4+1] + bq[c+1];
      oq.z = accq[i][jh*4+2] + bq[c+2];
      oq.w = accq[i][jh*4+3] + bq[c+3];
      *(float4*)(Yq + r * Nc + c) = oq;
      ok.x = acck[i][jh*4+0] + bk[c+0];
      ok.y = acck[i][jh*4+1] + bk[c+1];
      ok.z = acck[i][jh*4+2] + bk[c+2];
      ok.w = acck[i][jh*4+3] + bk[c+3];
      *(float4*)(Yk + r * Nc + c) = ok;
    }
  }
}

// ---------------------------------------------------------------------------
// v/p GEMM v4 (R17-verbatim, proven): f32 LDS, cvt->f64 at fragment read,
// same ascending-k f64 chain as R9 -> bit-identical outputs.
// ---------------------------------------------------------------------------
__global__ __launch_bounds__(256, 2)
void gemm_f64_v4(const float* __restrict__ A, const float* __restrict__ W,
                 const float* __restrict__ bias, float* __restrict__ Y,
                 int Nc, int K) {
  __shared__ float As[2][16][68];
  __shared__ float Ws[2][16][132];
  const int tid  = threadIdx.x;
  const int row0 = blockIdx.y * 64;
  const int col0 = blockIdx.x * 128;
  const int tx = tid & 15, ty = tid >> 4;
  const int ar = tid >> 2;
  const int ac = (tid & 3) << 2;

  double acc[4][8];
  #pragma unroll
  for (int i = 0; i < 4; ++i)
    #pragma unroll
    for (int j = 0; j < 8; ++j) acc[i][j] = 0.0;

  const float* Ap  = A + (size_t)(row0 + ar) * K + ac;
  const float* Wp0 = W + (size_t)(col0 + ar) * K + ac;
  const float* Wp1 = W + (size_t)(col0 + ar + 64) * K + ac;

  float4 pa  = *(const float4*)Ap;
  float4 pw0 = *(const float4*)Wp0;
  float4 pw1 = *(const float4*)Wp1;
  As[0][ac+0][ar] = pa.x; As[0][ac+1][ar] = pa.y; As[0][ac+2][ar] = pa.z; As[0][ac+3][ar] = pa.w;
  Ws[0][ac+0][ar] = pw0.x; Ws[0][ac+1][ar] = pw0.y; Ws[0][ac+2][ar] = pw0.z; Ws[0][ac+3][ar] = pw0.w;
  Ws[0][ac+0][ar+64] = pw1.x; Ws[0][ac+1][ar+64] = pw1.y; Ws[0][ac+2][ar+64] = pw1.z; Ws[0][ac+3][ar+64] = pw1.w;
  __syncthreads();

  int buf = 0;
  for (int k0 = 0; k0 < K; k0 += 16) {
    const bool last = (k0 + 16 >= K);
    if (!last) {
      pa  = *(const float4*)(Ap  + k0 + 16);
      pw0 = *(const float4*)(Wp0 + k0 + 16);
      pw1 = *(const float4*)(Wp1 + k0 + 16);
    }
    #pragma unroll
    for (int kk = 0; kk < 16; ++kk) {   // ascending k — exact chain order
      float4 av  = *(const float4*)&As[buf][kk][ty*4];
      float4 bv0 = *(const float4*)&Ws[buf][kk][tx*4];
      float4 bv1 = *(const float4*)&Ws[buf][kk][64 + tx*4];
      double a[4] = {(double)av.x, (double)av.y, (double)av.z, (double)av.w};
      double b[8] = {(double)bv0.x, (double)bv0.y, (double)bv0.z, (double)bv0.w,
                     (double)bv1.x, (double)bv1.y, (double)bv1.z, (double)bv1.w};
      #pragma unroll
      for (int i = 0; i < 4; ++i)
        #pragma unroll
        for (int j = 0; j < 8; ++j)
          acc[i][j] = fma(a[i], b[j], acc[i][j]);
    }
    if (!last) {
      int nb = buf ^ 1;
      As[nb][ac+0][ar] = pa.x; As[nb][ac+1][ar] = pa.y; As[nb][ac+2][ar] = pa.z; As[nb][ac+3][ar] = pa.w;
      Ws[nb][ac+0][ar] = pw0.x; Ws[nb][ac+1][ar] = pw0.y; Ws[nb][ac+2][ar] = pw0.z; Ws[nb][ac+3][ar] = pw0.w;
      Ws[nb][ac+0][ar+64] = pw1.x; Ws[nb][ac+1][ar+64] = pw1.y; Ws[nb][ac+2][ar+64] = pw1.z; Ws[nb][ac+3][ar+64] = pw1.w;
      __syncthreads();
      buf = nb;
    }
  }

  #pragma unroll
  for (int i = 0; i < 4; ++i) {
    size_t r = (size_t)(row0 + ty*4 + i);
    #pragma unroll
    for (int jh = 0; jh < 2; ++jh) {
      int c = col0 + jh*64 + tx*4;
      float4 o4;
      o4.x = (float)(acc[i][jh*4+0] + (double)bias[c+0]);
      o4.y = (float)(acc[i][jh*4+1] + (double)bias[c+1]);
      o4.z = (float)(acc[i][jh*4+2] + (double)bias[c+2]);
      o4.w = (float)(acc[i][jh*4+3] + (double)bias[c+3]);
      *(float4*)(Y + r * Nc + c) = o4;
    }
  }
}

// ---------------------------------------------------------------------------
// BN stats stage 1 (R1-verbatim)
// ---------------------------------------------------------------------------
__global__ __launch_bounds__(256)
void col_stats_partial(const float* __restrict__ Y, int Nc,
                       float* __restrict__ psum, float* __restrict__ psq) {
  const int r0 = blockIdx.x * 32;
  for (int c = threadIdx.x; c < Nc; c += 256) {
    float s = 0.f, q = 0.f;
    const float* p = Y + (size_t)r0 * Nc + c;
    for (int r = 0; r < 32; ++r) {
      float v = p[(size_t)r * Nc];
      s += v;
      q = fmaf(v, v, q);
    }
    psum[(size_t)blockIdx.x * Nc + c] = s;
    psq [(size_t)blockIdx.x * Nc + c] = q;
  }
}

// stage 2 (R1-verbatim)
__global__ void col_stats_final(const float* __restrict__ psum, const float* __restrict__ psq,
                                int Nc, const float* __restrict__ g, const float* __restrict__ beta,
                                float* __restrict__ chp) {
  int c = blockIdx.x * blockDim.x + threadIdx.x;
  if (c >= Nc) return;
  double s = 0.0, q = 0.0;
  for (int p = 0; p < 512; ++p) {
    s += (double)psum[(size_t)p * Nc + c];
    q += (double)psq [(size_t)p * Nc + c];
  }
  double mean = s / (double)M_;
  double var  = q / (double)M_ - mean * mean;
  float alpha = g[c] / sqrtf((float)var + 1e-5f);
  chp[2*c]   = alpha;
  chp[2*c+1] = fmaf(-(float)mean, alpha, beta[c]);
}

// stage 2 for v/p paths (R9-verbatim)
__global__ void col_stats_final_f64(const float* __restrict__ psum, const float* __restrict__ psq,
                                    int Nc, const float* __restrict__ g, const float* __restrict__ beta,
                                    double* __restrict__ chpd) {
  int c = blockIdx.x * blockDim.x + threadIdx.x;
  if (c >= Nc) return;
  double s = 0.0, q = 0.0;
  for (int p = 0; p < 512; ++p) {
    s += (double)psum[(size_t)p * Nc + c];
    q += (double)psq [(size_t)p * Nc + c];
  }
  double mean = s / (double)M_;
  double var  = q / (double)M_ - mean * mean;
  double alpha = (double)g[c] / sqrt(var + 1e-5);
  chpd[2*c]   = alpha;
  chpd[2*c+1] = (double)beta[c] - mean * alpha;
}

// ---------------------------------------------------------------------------
// BN + LIF masks (R1-verbatim) — q/k decisions, frozen
// ---------------------------------------------------------------------------
__global__ __launch_bounds__(256)
void bnlif_mask(const float* __restrict__ Y, const float* __restrict__ chp,
                unsigned long long* __restrict__ mask) {
  int lane = threadIdx.x & 63;
  int u  = blockIdx.x * 4 + (threadIdx.x >> 6);
  int bn = u >> 3, cg = u & 7;
  int c  = cg * 64 + lane;
  float alpha = chp[2*c], bb = chp[2*c+1];
  float v = 0.f;
  #pragma unroll
  for (int t = 0; t < 4; ++t) {
    float y  = Y[((size_t)(t * BNP_ + bn)) * C_ + c];
    float uu = fmaf(y, alpha, bb);
    v = v + (uu - v) * 0.5f;
    bool sp = (v >= 1.0f);
    unsigned long long m = __ballot(sp);
    if (sp) v = 0.f;
    if (lane == 0) mask[((size_t)(t * BNP_ + bn)) * H_ + cg] = m;
  }
}

// xo = x + BN(Yp) (R9-verbatim)
__global__ void bn_residual_f64(const float* __restrict__ Y, const double* __restrict__ chpd,
                                const float* __restrict__ x, float* __restrict__ out) {
  const long total4 = (long)M_ * C_ / 4;
  for (long i = (long)blockIdx.x * blockDim.x + threadIdx.x; i < total4;
       i += (long)gridDim.x * blockDim.x) {
    int c4 = (int)(i & (C_/4 - 1)) * 4;
    float4 y = ((const float4*)Y)[i];
    float4 xv = ((const float4*)x)[i];
    float4 r;
    r.x = (float)((double)xv.x + fma((double)y.x, chpd[2*(c4+0)], chpd[2*(c4+0)+1]));
    r.y = (float)((double)xv.y + fma((double)y.y, chpd[2*(c4+1)], chpd[2*(c4+1)+1]));
    r.z = (float)((double)xv.z + fma((double)y.z, chpd[2*(c4+2)], chpd[2*(c4+2)+1]));
    r.w = (float)((double)xv.w + fma((double)y.w, chpd[2*(c4+3)], chpd[2*(c4+3)+1]));
    ((float4*)out)[i] = r;
  }
}

// BN + LIF for f1 -> 64-bit spike masks per row (R15-verbatim)
__global__ __launch_bounds__(256)
void bnlif_hmask(const float* __restrict__ Y, const float* __restrict__ chp,
                 unsigned long long* __restrict__ hmask) {
  int c  = blockIdx.x * 256 + threadIdx.x;   // < 2048
  int bn = blockIdx.y;
  int lane = threadIdx.x & 63;
  int word = blockIdx.x * 4 + (threadIdx.x >> 6);
  float alpha = chp[2*c], bb = chp[2*c+1];
  float v = 0.f;
  #pragma unroll
  for (int t = 0; t < 4; ++t) {
    size_t row = (size_t)(t * BNP_ + bn);
    float uu = fmaf(Y[row * HID_ + c], alpha, bb);
    v = v + (uu - v) * 0.5f;
    bool sp = (v >= 1.f);
    unsigned long long m = __ballot(sp);
    if (sp) v = 0.f;
    if (lane == 0) hmask[row * 32 + word] = m;
  }
}

// BN + LIF for f2 + final residual (R1-verbatim)
__global__ __launch_bounds__(256)
void bnlif_final(const float* __restrict__ Y, const float* __restrict__ chp,
                 const float* __restrict__ xo, float* __restrict__ out) {
  int c  = blockIdx.x * 256 + threadIdx.x;   // < 512
  int bn = blockIdx.y;
  float alpha = chp[2*c], bb = chp[2*c+1];
  float v = 0.f;
  #pragma unroll
  for (int t = 0; t < 4; ++t) {
    size_t idx = ((size_t)(t * BNP_ + bn)) * C_ + c;
    float uu = fmaf(Y[idx], alpha, bb);
    v = v + (uu - v) * 0.5f;
    bool sp = (v >= 1.f);
    out[idx] = xo[idx] + (sp ? 1.f : 0.f);
    if (sp) v = 0.f;
  }
}

// ---------------------------------------------------------------------------
// Attention with fused BN(v) at V-load (R17-verbatim, proven)
// ---------------------------------------------------------------------------
__global__ __launch_bounds__(256)
void attn_kernel_f64(const unsigned long long* __restrict__ qmask,
                     const unsigned long long* __restrict__ kmask,
                     const float* __restrict__ vraw, const double* __restrict__ chpd,
                     float* __restrict__ o) {
  __shared__ unsigned long long km[256];
  __shared__ float vt[256][64];
  int rb  = blockIdx.x & 3;
  int tbh = blockIdx.x >> 2;
  int h   = tbh & 7, tb = tbh >> 3;
  int tid = threadIdx.x;

  km[tid] = kmask[(size_t)(tb * 256 + tid) * H_ + h];
  const float* vbase = vraw + (size_t)tb * 256 * C_ + h * 64;
  #pragma unroll
  for (int i = 0; i < 16; ++i) {
    int f = i * 256 + tid;
    int r = f >> 4, c4 = f & 15;
    float4 y = *(const float4*)(vbase + (size_t)r * C_ + c4 * 4);
    int ch = h * 64 + c4 * 4;
    vt[r][c4*4+0] = (float)fma((double)y.x, chpd[2*(ch+0)], chpd[2*(ch+0)+1]);
    vt[r][c4*4+1] = (float)fma((double)y.y, chpd[2*(ch+1)], chpd[2*(ch+1)+1]);
    vt[r][c4*4+2] = (float)fma((double)y.z, chpd[2*(ch+2)], chpd[2*(ch+2)+1]);
    vt[r][c4*4+3] = (float)fma((double)y.w, chpd[2*(ch+3)], chpd[2*(ch+3)+1]);
  }
  int lane = tid & 63, w = tid >> 6;
  int nr = lane & 15, dg = lane >> 4;
  int n  = rb * 64 + w * 16 + nr;
  unsigned long long qm = qmask[(size_t)(tb * 256 + n) * H_ + h];
  __syncthreads();

  double acc[16];
  #pragma unroll
  for (int j = 0; j < 16; ++j) acc[j] = 0.0;

  for (int m = 0; m < 256; ++m) {
    double s = (double)__popcll(qm & km[m]) * 0.125;
    #pragma unroll
    for (int j = 0; j < 4; ++j) {
      float4 vv = *(const float4*)&vt[m][dg * 16 + j * 4];
      acc[j*4+0] = fma(s, (double)vv.x, acc[j*4+0]);
      acc[j*4+1] = fma(s, (double)vv.y, acc[j*4+1]);
      acc[j*4+2] = fma(s, (double)vv.z, acc[j*4+2]);
      acc[j*4+3] = fma(s, (double)vv.w, acc[j*4+3]);
    }
  }
  float* orow = o + (size_t)(tb * 256 + n) * C_ + h * 64 + dg * 16;
  #pragma unroll
  for (int j = 0; j < 4; ++j)
    *(float4*)(orow + j * 4) = make_float4((float)acc[j*4], (float)acc[j*4+1],
                                           (float)acc[j*4+2], (float)acc[j*4+3]);
}

// ---------------------------------------------------------------------------
extern "C" void kernel_launch(void* const* d_in, const int* in_sizes, int n_in,
                              void* d_out, int out_size, void* d_ws, size_t ws_size,
                              hipStream_t stream) {
  const float* x    = (const float*)d_in[0];
  const float* qw   = (const float*)d_in[2];
  const float* qb   = (const float*)d_in[3];
  const float* qg   = (const float*)d_in[4];
  const float* qbe  = (const float*)d_in[5];
  const float* kw   = (const float*)d_in[6];
  const float* kb   = (const float*)d_in[7];
  const float* kg   = (const float*)d_in[8];
  const float* kbe  = (const float*)d_in[9];
  const float* vw   = (const float*)d_in[10];
  const float* vb   = (const float*)d_in[11];
  const float* vg   = (const float*)d_in[12];
  const float* vbe  = (const float*)d_in[13];
  const float* pw   = (const float*)d_in[14];
  const float* pb   = (const float*)d_in[15];
  const float* pg   = (const float*)d_in[16];
  const float* pbe  = (const float*)d_in[17];
  const float* f1w  = (const float*)d_in[18];
  const float* f1b  = (const float*)d_in[19];
  const float* f1g  = (const float*)d_in[20];
  const float* f1be = (const float*)d_in[21];
  const float* f2w  = (const float*)d_in[22];
  const float* f2b  = (const float*)d_in[23];
  const float* f2g  = (const float*)d_in[24];
  const float* f2be = (const float*)d_in[25];

  char* ws = (char*)d_ws;
  float* bufY = (float*)(ws);                                   // 128 MB
  float* bufK = bufY + 8388608;                                 // k at bufY+32MB
  float* bufV = (float*)(ws + 134217728ull);                    //  32 MB (hmask home)
  float* bufO = (float*)(ws + 167772160ull);                    //  32 MB (o, then xo)
  unsigned long long* qmask = (unsigned long long*)(ws + 201326592ull);
  unsigned long long* kmask = (unsigned long long*)(ws + 202375168ull);
  float* psum = (float*)(ws + 203423744ull);                    // 4 MB
  float* psq  = (float*)(ws + 207618048ull);                    // 4 MB
  float* chp  = (float*)(ws + 211812352ull);                    // 16 KB
  double* chpd = (double*)(ws + 211828736ull);                  // 8 KB
  unsigned long long* hmask = (unsigned long long*)bufV;        // 4 MB

  float* out = (float*)d_out;

  // ---- fused q+k GEMM ----
  gemm_f32_qk<<<dim3(4,256), 256, 0, stream>>>(x, qw, qb, kw, kb, bufY, bufK, C_, C_);
  col_stats_partial<<<512, 256, 0, stream>>>(bufY, C_, psum, psq);
  col_stats_final<<<2, 256, 0, stream>>>(psum, psq, C_, qg, qbe, chp);
  bnlif_mask<<<8192, 256, 0, stream>>>(bufY, chp, qmask);
  col_stats_partial<<<512, 256, 0, stream>>>(bufK, C_, psum, psq);
  col_stats_final<<<2, 256, 0, stream>>>(psum, psq, C_, kg, kbe, chp);
  bnlif_mask<<<8192, 256, 0, stream>>>(bufK, chp, kmask);
  // ---- v path (f64 acc, f32 LDS) ----
  gemm_f64_v4<<<dim3(4,256), 256, 0, stream>>>(x, vw, vb, bufY, C_, C_);
  col_stats_partial<<<512, 256, 0, stream>>>(bufY, C_, psum, psq);
  col_stats_final_f64<<<2, 256, 0, stream>>>(psum, psq, C_, vg, vbe, chpd);
  // ---- attention (BN(v) fused at V-load) ----
  attn_kernel_f64<<<2048, 256, 0, stream>>>(qmask, kmask, bufY, chpd, bufO);
  // ---- projection + residual ----
  gemm_f64_v4<<<dim3(4,256), 256, 0, stream>>>(bufO, pw, pb, bufY, C_, C_);
  col_stats_partial<<<512, 256, 0, stream>>>(bufY, C_, psum, psq);
  col_stats_final_f64<<<2, 256, 0, stream>>>(psum, psq, C_, pg, pbe, chpd);
  bn_residual_f64<<<2048, 256, 0, stream>>>(bufY, chpd, x, bufO);
  // ---- MLP f1 (proven 128x128 tile) ----
  gemm_f32_t128<<<dim3(16,128), 256, 0, stream>>>(bufO, f1w, f1b, bufY, HID_, C_);
  col_stats_partial<<<512, 256, 0, stream>>>(bufY, HID_, psum, psq);
  col_stats_final<<<8, 256, 0, stream>>>(psum, psq, HID_, f1g, f1be, chp);
  bnlif_hmask<<<dim3(8,4096), 256, 0, stream>>>(bufY, chp, hmask);
  // ---- MLP f2: SPARSE over spike masks (proven serial walk) ----
  gemm_f32_f2sparse<<<dim3(4,256), 256, 0, stream>>>(hmask, f2w, f2b, bufY);
  col_stats_partial<<<512, 256, 0, stream>>>(bufY, C_, psum, psq);
  col_stats_final<<<2, 256, 0, stream>>>(psum, psq, C_, f2g, f2be, chp);
  bnlif_final<<<dim3(2,4096), 256, 0, stream>>>(bufY, chp, bufO, out);
}